// Round 6
// baseline (680.486 us; speedup 1.0000x reference)
//
#include <hip/hip_runtime.h>
#include <hip/hip_fp16.h>

#define NN 100000   // nodes
#define NE 3200000  // edges
#define NF 128      // in features
#define EM 20       // embed
#define NC 10       // classes
#define NG 64       // graphs

#define NB 782      // dst buckets of 128 nodes: ceil(100000/128)
#define CAPB 4608   // per-bucket capacity: mean 4096, +8 sigma
#define T 4096      // edges per scatter block
#define SBLK 512    // scatter block threads

#define PLANE_HALVES ((size_t)NN * 16)  // fp16 plane: 16 halves (32B) per node, 10 used

// ---------------- bucketed counting-sort scatter ----------------
__global__ void k_scatter(const int* __restrict__ src, const int* __restrict__ dst,
                          const float* __restrict__ w, int* __restrict__ gcursor,
                          uint2* __restrict__ barr) {
    __shared__ unsigned int cnt[NB];
    __shared__ unsigned int off[NB];
    __shared__ unsigned int gbase[NB];
    __shared__ uint2 staged[T];                 // aliased as scan scratch (disjoint phases)
    __shared__ unsigned short bkt[T];
    unsigned int* scratch = (unsigned int*)staged;
    int tid = threadIdx.x;
    long E0 = (long)blockIdx.x * T;
    int tot = (int)min((long)T, (long)NE - E0);
    for (int i = tid; i < NB; i += SBLK) cnt[i] = 0;
    for (int i = tid; i < 1024; i += SBLK) scratch[i] = 0;
    __syncthreads();
    for (int k = 0; k < T / SBLK; ++k) {
        int e = k * SBLK + tid;
        if (e < tot) atomicAdd(&cnt[((unsigned)dst[E0 + e]) >> 7], 1u);
    }
    __syncthreads();
    for (int i = tid; i < NB; i += SBLK) scratch[i] = cnt[i];
    __syncthreads();
    for (int d = 1; d < 1024; d <<= 1) {
        unsigned int v[1024 / SBLK];
#pragma unroll
        for (int q = 0; q < 1024 / SBLK; ++q) {
            int idx = q * SBLK + tid;
            v[q] = (idx >= d) ? scratch[idx - d] : 0u;
        }
        __syncthreads();
#pragma unroll
        for (int q = 0; q < 1024 / SBLK; ++q) scratch[q * SBLK + tid] += v[q];
        __syncthreads();
    }
    for (int i = tid; i < NB; i += SBLK) off[i] = scratch[i] - cnt[i];
    __syncthreads();
    for (int i = tid; i < NB; i += SBLK) {
        unsigned int c = cnt[i];
        gbase[i] = c ? (unsigned int)atomicAdd(&gcursor[i], (int)c) : 0u;
        cnt[i] = 0;
    }
    __syncthreads();
    for (int k = 0; k < T / SBLK; ++k) {
        int e = k * SBLK + tid;
        if (e < tot) {
            long ge = E0 + e;
            unsigned int d = (unsigned)dst[ge];
            unsigned int b = d >> 7;
            unsigned int slot = atomicAdd(&cnt[b], 1u);
            unsigned int pos = off[b] + slot;
            staged[pos] = make_uint2((((unsigned)src[ge]) << 7) | (d & 127u),
                                     __float_as_uint(w[ge]));
            bkt[pos] = (unsigned short)b;
        }
    }
    __syncthreads();
    for (int i = tid; i < tot; i += SBLK) {
        unsigned int b = bkt[i];
        unsigned int gpos = gbase[b] + ((unsigned)i - off[b]);
        if (gpos < CAPB) barr[(size_t)b * CAPB + gpos] = staged[i];
    }
}

// ---------------- per-bucket weighted degree -> dinv ----------------
__global__ void k_degb(const int* __restrict__ gcursor, const uint2* __restrict__ barr,
                       float* __restrict__ dinv) {
    __shared__ float dacc[128];
    int b = blockIdx.x, tid = threadIdx.x;
    if (tid < 128) dacc[tid] = 0.f;
    __syncthreads();
    int cntb = min(gcursor[b], CAPB);
    const uint2* row = barr + (size_t)b * CAPB;
    for (int i = tid; i < cntb; i += 1024) {
        uint2 r = row[i];
        atomicAdd(&dacc[r.x & 127u], __uint_as_float(r.y));
    }
    __syncthreads();
    if (tid < 128) {
        int gd = b * 128 + tid;
        if (gd < NN) dinv[gd] = rsqrtf(1.0f + dacc[tid]);  // +1 = self-loop
    }
}

// ---------------- fold dinv[src] into record weight ----------------
__global__ void k_fix(const int* __restrict__ gcursor, uint2* __restrict__ barr,
                      const float* __restrict__ dinv) {
    int b = blockIdx.x;
    int cntb = min(gcursor[b], CAPB);
    uint2* row = barr + (size_t)b * CAPB;
    for (int i = threadIdx.x; i < cntb; i += 256) {
        uint2 r = row[i];
        row[i].y = __float_as_uint(dinv[r.x >> 7] * __uint_as_float(r.y));
    }
}

// ---------------- xw = x @ W, LDS-tiled ----------------
__global__ void k_xw(const float* __restrict__ x, const float* __restrict__ W,
                     float* __restrict__ xw) {
    __shared__ float xs[64 * 129];
    __shared__ float Ws[NF * EM];
    int base = blockIdx.x * 64;
    for (int i = threadIdx.x; i < NF * EM; i += 256) Ws[i] = W[i];
    const float4* xg = (const float4*)(x + (size_t)base * NF);
    for (int v = threadIdx.x; v < 64 * NF / 4; v += 256) {
        int fidx = v * 4;
        size_t gidx = (size_t)base * NF + fidx;
        float4 val = (gidx + 3 < (size_t)NN * NF) ? xg[v] : make_float4(0.f, 0.f, 0.f, 0.f);
        int r = fidx / NF, c = fidx % NF;
        float* p = xs + r * 129 + c;
        p[0] = val.x; p[1] = val.y; p[2] = val.z; p[3] = val.w;
    }
    __syncthreads();
    int n = threadIdx.x & 63;
    int j0 = (threadIdx.x >> 6) * 5;
    if (base + n >= NN) return;
    float acc[5] = {0.f, 0.f, 0.f, 0.f, 0.f};
    const float* xr = xs + n * 129;
#pragma unroll 4
    for (int k = 0; k < NF; ++k) {
        float xv = xr[k];
        const float* wr = Ws + k * EM + j0;
#pragma unroll
        for (int jj = 0; jj < 5; ++jj) acc[jj] = fmaf(xv, wr[jj], acc[jj]);
    }
    float* o = xw + (size_t)(base + n) * EM + j0;
#pragma unroll
    for (int jj = 0; jj < 5; ++jj) o[jj] = acc[jj];
}

// ---------------- pack xw into two fp16 planes (dims 0-9 / 10-19) ----------------
__global__ void k_half(const float* __restrict__ xw, __half* __restrict__ xwh) {
    int t = blockIdx.x * 256 + threadIdx.x;
    if (t >= NN * EM) return;
    int n = t / EM, j = t % EM;
    int p = j / 10, jj = j - p * 10;
    xwh[(size_t)p * PLANE_HALVES + (size_t)n * 16 + jj] = __float2half(xw[t]);
}

// ---------------- per-bucket aggregate from L2-resident fp16 plane ----------------
// pass 0: dims 0-9 -> out1p0; pass 1: dims 10-19 + fused epilogue -> embed
__global__ void k_aggr(const int* __restrict__ gcursor, const uint2* __restrict__ barr,
                       const __half* __restrict__ xwh, const float* __restrict__ dinv,
                       const float* __restrict__ xw, const float* __restrict__ b,
                       float* __restrict__ out1p0, float* __restrict__ embed, int pass) {
    __shared__ float acc[128 * 11];   // stride 11 coprime with 32 banks
    int bk = blockIdx.x, tid = threadIdx.x;
    for (int i = tid; i < 128 * 11; i += 1024) acc[i] = 0.f;
    __syncthreads();
    int cntb = min(gcursor[bk], CAPB);
    const unsigned long long* row64 = (const unsigned long long*)(barr + (size_t)bk * CAPB);
    const uint4* plane4 = (const uint4*)(xwh + (size_t)pass * PLANE_HALVES);
    const uint*  plane1 = (const uint*)plane4;
    for (int i = tid; i < cntb; i += 1024) {
        unsigned long long r = __builtin_nontemporal_load(&row64[i]);
        unsigned int key = (unsigned int)r;
        unsigned int s = key >> 7;
        unsigned int dl = key & 127u;
        float nw = __uint_as_float((unsigned int)(r >> 32));  // already dinv[src]*w
        uint4 h4 = plane4[(size_t)s * 2];           // halves 0-7 (16B aligned)
        uint  h2 = plane1[(size_t)s * 8 + 4];       // halves 8-9
        const __half2* hh = (const __half2*)&h4;
        float2 f0 = __half22float2(hh[0]);
        float2 f1 = __half22float2(hh[1]);
        float2 f2 = __half22float2(hh[2]);
        float2 f3 = __half22float2(hh[3]);
        float2 f4 = __half22float2(*(const __half2*)&h2);
        float* a = acc + dl * 11;
        atomicAdd(a + 0, f0.x * nw); atomicAdd(a + 1, f0.y * nw);
        atomicAdd(a + 2, f1.x * nw); atomicAdd(a + 3, f1.y * nw);
        atomicAdd(a + 4, f2.x * nw); atomicAdd(a + 5, f2.y * nw);
        atomicAdd(a + 6, f3.x * nw); atomicAdd(a + 7, f3.y * nw);
        atomicAdd(a + 8, f4.x * nw); atomicAdd(a + 9, f4.y * nw);
    }
    __syncthreads();
    if (tid < 128) {
        int gd = bk * 128 + tid;
        if (gd < NN) {
            float dv = dinv[gd];
            const float* xd = xw + (size_t)gd * EM + pass * 10;
            const float* a = acc + tid * 11;
            float r[10];
#pragma unroll
            for (int j = 0; j < 10; ++j)
                r[j] = dv * fmaf(xd[j], dv, a[j]) + b[pass * 10 + j];
            if (pass == 0) {
                float* o = out1p0 + (size_t)gd * 10;
#pragma unroll
                for (int j = 0; j < 10; ++j) o[j] = r[j];
            } else {
                float r0[10];
                float ss = 0.f;
                const float* o0 = out1p0 + (size_t)gd * 10;
#pragma unroll
                for (int j = 0; j < 10; ++j) { r0[j] = o0[j]; ss = fmaf(r0[j], r0[j], ss); }
#pragma unroll
                for (int j = 0; j < 10; ++j) ss = fmaf(r[j], r[j], ss);
                float inv = 1.0f / fmaxf(sqrtf(ss), 1e-12f);
                float* o = embed + (size_t)gd * EM;
#pragma unroll
                for (int j = 0; j < 10; ++j) {
                    float e0 = r0[j] * inv;
                    float e1 = r[j] * inv;
                    o[j]      = e0 > 0.f ? e0 : 0.f;
                    o[10 + j] = e1 > 0.f ? e1 : 0.f;
                }
            }
        }
    }
}

// ---------------- graph boundaries (batch sorted) ----------------
__global__ void k_bound(const int* __restrict__ batch, int* __restrict__ gstart) {
    int n = blockIdx.x * 256 + threadIdx.x;
    if (n >= NN) return;
    int bn = batch[n];
    if (n == 0) {
        for (int g = 0; g <= bn; ++g) gstart[g] = 0;
    } else {
        int bp = batch[n - 1];
        for (int g = bp + 1; g <= bn; ++g) gstart[g] = n;
    }
    if (n == NN - 1) {
        for (int g = bn + 1; g <= NG; ++g) gstart[g] = NN;
    }
}

// ---------------- per-graph pool (max+mean) + final linear ----------------
__global__ void k_poolfinal(const float* __restrict__ embed, const int* __restrict__ gstart,
                            const float* __restrict__ lw, const float* __restrict__ lb,
                            float* __restrict__ out) {
    __shared__ float cross[4][40];
    __shared__ float pooled[40];
    int g = blockIdx.x;
    int s0 = gstart[g], s1 = gstart[g + 1];
    int cnt = s1 - s0;
    float mx[EM], sm[EM];
#pragma unroll
    for (int j = 0; j < EM; ++j) { mx[j] = 0.f; sm[j] = 0.f; }
    for (int n = s0 + threadIdx.x; n < s1; n += 256) {
        const float4* e = (const float4*)(embed + (size_t)n * EM);
#pragma unroll
        for (int c = 0; c < 5; ++c) {
            float4 v = e[c];
            int j = c * 4;
            mx[j+0] = fmaxf(mx[j+0], v.x); sm[j+0] += v.x;
            mx[j+1] = fmaxf(mx[j+1], v.y); sm[j+1] += v.y;
            mx[j+2] = fmaxf(mx[j+2], v.z); sm[j+2] += v.z;
            mx[j+3] = fmaxf(mx[j+3], v.w); sm[j+3] += v.w;
        }
    }
#pragma unroll
    for (int o = 32; o > 0; o >>= 1) {
#pragma unroll
        for (int j = 0; j < EM; ++j) {
            mx[j] = fmaxf(mx[j], __shfl_xor(mx[j], o));
            sm[j] += __shfl_xor(sm[j], o);
        }
    }
    int wave = threadIdx.x >> 6, lane = threadIdx.x & 63;
    if (lane == 0) {
#pragma unroll
        for (int j = 0; j < EM; ++j) { cross[wave][j] = mx[j]; cross[wave][EM + j] = sm[j]; }
    }
    __syncthreads();
    if (threadIdx.x < 40) {
        int j = threadIdx.x;
        float v = cross[0][j];
        if (j < EM) v = fmaxf(fmaxf(v, cross[1][j]), fmaxf(cross[2][j], cross[3][j]));
        else        v = v + cross[1][j] + cross[2][j] + cross[3][j];
        if (j >= EM) v *= 1.0f / fmaxf((float)cnt, 1.0f);
        pooled[j] = v;
    }
    __syncthreads();
    if (threadIdx.x < NC) {
        int c = threadIdx.x;
        float acc = lb[c];
#pragma unroll
        for (int j = 0; j < 2 * EM; ++j) acc = fmaf(pooled[j], lw[j * NC + c], acc);
        out[g * NC + c] = acc;
    }
}

extern "C" void kernel_launch(void* const* d_in, const int* in_sizes, int n_in,
                              void* d_out, int out_size, void* d_ws, size_t ws_size,
                              hipStream_t stream) {
    const float* x     = (const float*)d_in[0];
    const int*   ei    = (const int*)d_in[1];
    const float* ew    = (const float*)d_in[2];
    const int*   batch = (const int*)d_in[3];
    const float* W     = (const float*)d_in[4];
    const float* b     = (const float*)d_in[5];
    const float* lw    = (const float*)d_in[6];
    const float* lb    = (const float*)d_in[7];
    float* out = (float*)d_out;

    char* ws = (char*)d_ws;
    int*    gcursor = (int*)ws;    ws += 4096;
    int*    gstart  = (int*)ws;    ws += 1024;
    float*  dinv    = (float*)ws;  ws += (size_t)NN * 4;            // 400 KB
    float*  xw      = (float*)ws;  ws += (size_t)NN * EM * 4;       // 8 MB
    __half* xwh     = (__half*)ws; ws += 2 * PLANE_HALVES * 2;      // 6.4 MB
    float*  out1p0  = (float*)ws;  ws += (size_t)NN * 10 * 4;       // 4 MB
    float*  embed   = (float*)ws;  ws += (size_t)NN * EM * 4;       // 8 MB
    uint2*  barr    = (uint2*)ws;                                   // 28.8 MB

    const int* srcp = ei;
    const int* dstp = ei + NE;

    (void)hipMemsetAsync(gcursor, 0, 4096, stream);
    k_scatter<<<(NE + T - 1) / T, SBLK, 0, stream>>>(srcp, dstp, ew, gcursor, barr);
    k_degb<<<NB, 1024, 0, stream>>>(gcursor, barr, dinv);
    k_fix<<<NB, 256, 0, stream>>>(gcursor, barr, dinv);
    k_xw<<<(NN + 63) / 64, 256, 0, stream>>>(x, W, xw);
    k_half<<<(NN * EM + 255) / 256, 256, 0, stream>>>(xw, xwh);
    k_aggr<<<NB, 1024, 0, stream>>>(gcursor, barr, xwh, dinv, xw, b, out1p0, embed, 0);
    k_aggr<<<NB, 1024, 0, stream>>>(gcursor, barr, xwh, dinv, xw, b, out1p0, embed, 1);
    k_bound<<<(NN + 255) / 256, 256, 0, stream>>>(batch, gstart);
    k_poolfinal<<<NG, 256, 0, stream>>>(embed, gstart, lw, lb, out);
}

// Round 7
// 353.308 us; speedup vs baseline: 1.9260x; 1.9260x over previous
//
#include <hip/hip_runtime.h>
#include <hip/hip_fp16.h>

#define NN 100000   // nodes
#define NE 3200000  // edges
#define NF 128      // in features
#define EM 20       // embed
#define NC 10       // classes
#define NG 64       // graphs

#define NB 782      // dst buckets of 128 nodes
#define CAPB 4608   // per-bucket capacity (mean 4096, +8 sigma)
#define T 4096      // edges per scatter block
#define SBLK 512    // scatter block threads

#define PLANE_HALVES ((size_t)NN * 16)  // fp16 plane: 16 halves (32B) per node, 10 used

// ---------------- bucketed counting-sort scatter ----------------
__global__ void k_scatter(const int* __restrict__ src, const int* __restrict__ dst,
                          const float* __restrict__ w, int* __restrict__ gcursor,
                          uint2* __restrict__ barr) {
    __shared__ unsigned int cnt[NB];
    __shared__ unsigned int off[NB];
    __shared__ unsigned int gbase[NB];
    __shared__ uint2 staged[T];                 // aliased as scan scratch (disjoint phases)
    __shared__ unsigned short bkt[T];
    unsigned int* scratch = (unsigned int*)staged;
    int tid = threadIdx.x;
    long E0 = (long)blockIdx.x * T;
    int tot = (int)min((long)T, (long)NE - E0);
    for (int i = tid; i < NB; i += SBLK) cnt[i] = 0;
    for (int i = tid; i < 1024; i += SBLK) scratch[i] = 0;
    __syncthreads();
    for (int k = 0; k < T / SBLK; ++k) {
        int e = k * SBLK + tid;
        if (e < tot) atomicAdd(&cnt[((unsigned)dst[E0 + e]) >> 7], 1u);
    }
    __syncthreads();
    for (int i = tid; i < NB; i += SBLK) scratch[i] = cnt[i];
    __syncthreads();
    for (int d = 1; d < 1024; d <<= 1) {
        unsigned int v[1024 / SBLK];
#pragma unroll
        for (int q = 0; q < 1024 / SBLK; ++q) {
            int idx = q * SBLK + tid;
            v[q] = (idx >= d) ? scratch[idx - d] : 0u;
        }
        __syncthreads();
#pragma unroll
        for (int q = 0; q < 1024 / SBLK; ++q) scratch[q * SBLK + tid] += v[q];
        __syncthreads();
    }
    for (int i = tid; i < NB; i += SBLK) off[i] = scratch[i] - cnt[i];
    __syncthreads();
    for (int i = tid; i < NB; i += SBLK) {
        unsigned int c = cnt[i];
        gbase[i] = c ? (unsigned int)atomicAdd(&gcursor[i], (int)c) : 0u;
        cnt[i] = 0;
    }
    __syncthreads();
    for (int k = 0; k < T / SBLK; ++k) {
        int e = k * SBLK + tid;
        if (e < tot) {
            long ge = E0 + e;
            unsigned int d = (unsigned)dst[ge];
            unsigned int b = d >> 7;
            unsigned int slot = atomicAdd(&cnt[b], 1u);
            unsigned int pos = off[b] + slot;
            staged[pos] = make_uint2((((unsigned)src[ge]) << 7) | (d & 127u),
                                     __float_as_uint(w[ge]));
            bkt[pos] = (unsigned short)b;
        }
    }
    __syncthreads();
    for (int i = tid; i < tot; i += SBLK) {
        unsigned int b = bkt[i];
        unsigned int gpos = gbase[b] + ((unsigned)i - off[b]);
        if (gpos < CAPB) barr[(size_t)b * CAPB + gpos] = staged[i];
    }
}

// ---------------- per-bucket dl-sort -> CSR rowptr + dinv ----------------
// One returning int atomic per edge (histogram+slot), then scan, LDS scatter,
// coalesced write-back. Weighted degree = atomic-free run-sum over sorted LDS.
__global__ __launch_bounds__(1024) void k_sortb(const int* __restrict__ gcursor,
                                                unsigned long long* __restrict__ barr64,
                                                int* __restrict__ rowptrs,
                                                float* __restrict__ dinv) {
    __shared__ unsigned long long srt[CAPB];
    __shared__ unsigned int cnt[128];
    __shared__ unsigned int off[128];
    int bk = blockIdx.x, tid = threadIdx.x;
    if (tid < 128) cnt[tid] = 0;
    __syncthreads();
    int cntb = min(gcursor[bk], CAPB);
    unsigned long long* row = barr64 + (size_t)bk * CAPB;
    unsigned long long rec[5];
    unsigned int pos[5];
    int K = 0;
    for (int e = tid; e < cntb; e += 1024) {
        rec[K] = row[e];
        pos[K] = atomicAdd(&cnt[(unsigned)rec[K] & 127u], 1u);
        ++K;
    }
    __syncthreads();
    // inclusive scan of cnt into off (128 entries)
    if (tid < 128) off[tid] = cnt[tid];
    __syncthreads();
    for (int d = 1; d < 128; d <<= 1) {
        unsigned int v = 0;
        if (tid < 128 && tid >= (unsigned)d) v = off[tid - d];
        __syncthreads();
        if (tid < 128 && tid >= (unsigned)d) off[tid] += v;
        __syncthreads();
    }
    // scatter into sorted order: exclusive base = off[dl] - cnt[dl]
    for (int k = 0; k < K; ++k) {
        unsigned int dl = (unsigned)rec[k] & 127u;
        srt[off[dl] - cnt[dl] + pos[k]] = rec[k];
    }
    __syncthreads();
    // coalesced write-back (in-place safe: all reads done)
    for (int e = tid; e < cntb; e += 1024) row[e] = srt[e];
    if (tid < 128) rowptrs[bk * 129 + tid] = (int)(off[tid] - cnt[tid]);
    if (tid == 0) rowptrs[bk * 129 + 128] = cntb;
    // weighted degree per dst: serial run-sum (no atomics)
    if (tid < 128) {
        unsigned int s0 = off[tid] - cnt[tid], s1 = off[tid];
        float s = 1.0f;  // self-loop
        for (unsigned int i = s0; i < s1; ++i)
            s += __uint_as_float((unsigned int)(srt[i] >> 32));
        int gd = bk * 128 + tid;
        if (gd < NN) dinv[gd] = rsqrtf(s);
    }
}

// ---------------- fold dinv[src] into record weight ----------------
__global__ void k_fix(const int* __restrict__ gcursor, uint2* __restrict__ barr,
                      const float* __restrict__ dinv) {
    int b = blockIdx.x;
    int cntb = min(gcursor[b], CAPB);
    uint2* row = barr + (size_t)b * CAPB;
    for (int i = threadIdx.x; i < cntb; i += 256) {
        uint2 r = row[i];
        row[i].y = __float_as_uint(dinv[r.x >> 7] * __uint_as_float(r.y));
    }
}

// ---------------- xw = x @ W, LDS-tiled; also emits fp16 planes ----------------
__global__ void k_xw(const float* __restrict__ x, const float* __restrict__ W,
                     float* __restrict__ xw, __half* __restrict__ xwh) {
    __shared__ float xs[64 * 129];
    __shared__ float Ws[NF * EM];
    int base = blockIdx.x * 64;
    for (int i = threadIdx.x; i < NF * EM; i += 256) Ws[i] = W[i];
    const float4* xg = (const float4*)(x + (size_t)base * NF);
    for (int v = threadIdx.x; v < 64 * NF / 4; v += 256) {
        int fidx = v * 4;
        size_t gidx = (size_t)base * NF + fidx;
        float4 val = (gidx + 3 < (size_t)NN * NF) ? xg[v] : make_float4(0.f, 0.f, 0.f, 0.f);
        int r = fidx / NF, c = fidx % NF;
        float* p = xs + r * 129 + c;
        p[0] = val.x; p[1] = val.y; p[2] = val.z; p[3] = val.w;
    }
    __syncthreads();
    int n = threadIdx.x & 63;
    int jg = threadIdx.x >> 6;       // 0..3
    int j0 = jg * 5;
    if (base + n >= NN) return;
    float acc[5] = {0.f, 0.f, 0.f, 0.f, 0.f};
    const float* xr = xs + n * 129;
#pragma unroll 4
    for (int k = 0; k < NF; ++k) {
        float xv = xr[k];
        const float* wr = Ws + k * EM + j0;
#pragma unroll
        for (int jj = 0; jj < 5; ++jj) acc[jj] = fmaf(xv, wr[jj], acc[jj]);
    }
    float* o = xw + (size_t)(base + n) * EM + j0;
#pragma unroll
    for (int jj = 0; jj < 5; ++jj) o[jj] = acc[jj];
    // fp16 plane: plane = jg>>1, half-offset = (jg&1)*5
    __half* ph = xwh + (size_t)(jg >> 1) * PLANE_HALVES + (size_t)(base + n) * 16 + (jg & 1) * 5;
#pragma unroll
    for (int jj = 0; jj < 5; ++jj) ph[jj] = __float2half(acc[jj]);
}

// ---------------- CSR aggregate, register accumulation, no atomics ----------------
// 4 threads per dst; 2-step shfl_xor reduce; pass 0 -> out1p0, pass 1 -> fused epilogue
__global__ void k_aggr2(const int* __restrict__ rowptrs, const unsigned long long* __restrict__ barr64,
                        const __half* __restrict__ xwh, const float* __restrict__ dinv,
                        const float* __restrict__ xw, const float* __restrict__ b,
                        float* __restrict__ out1p0, float* __restrict__ embed, int pass) {
    int bk = blockIdx.x, tid = threadIdx.x;   // 512 threads
    int d = tid >> 2, sub = tid & 3;
    int s0 = rowptrs[bk * 129 + d], s1 = rowptrs[bk * 129 + d + 1];
    const unsigned long long* row = barr64 + (size_t)bk * CAPB;
    const uint4* plane4 = (const uint4*)(xwh + (size_t)pass * PLANE_HALVES);
    const uint*  plane1 = (const uint*)plane4;
    float acc[10];
#pragma unroll
    for (int j = 0; j < 10; ++j) acc[j] = 0.f;
    for (int e = s0 + sub; e < s1; e += 4) {
        unsigned long long r = __builtin_nontemporal_load(&row[e]);
        unsigned int s = ((unsigned int)r) >> 7;
        float nw = __uint_as_float((unsigned int)(r >> 32));  // dinv[src]*w
        uint4 h4 = plane4[(size_t)s * 2];
        uint  h2 = plane1[(size_t)s * 8 + 4];
        const __half2* hh = (const __half2*)&h4;
        float2 f0 = __half22float2(hh[0]);
        float2 f1 = __half22float2(hh[1]);
        float2 f2 = __half22float2(hh[2]);
        float2 f3 = __half22float2(hh[3]);
        float2 f4 = __half22float2(*(const __half2*)&h2);
        acc[0] = fmaf(f0.x, nw, acc[0]); acc[1] = fmaf(f0.y, nw, acc[1]);
        acc[2] = fmaf(f1.x, nw, acc[2]); acc[3] = fmaf(f1.y, nw, acc[3]);
        acc[4] = fmaf(f2.x, nw, acc[4]); acc[5] = fmaf(f2.y, nw, acc[5]);
        acc[6] = fmaf(f3.x, nw, acc[6]); acc[7] = fmaf(f3.y, nw, acc[7]);
        acc[8] = fmaf(f4.x, nw, acc[8]); acc[9] = fmaf(f4.y, nw, acc[9]);
    }
#pragma unroll
    for (int j = 0; j < 10; ++j) {
        acc[j] += __shfl_xor(acc[j], 1);
        acc[j] += __shfl_xor(acc[j], 2);
    }
    if (sub == 0) {
        int gd = bk * 128 + d;
        if (gd < NN) {
            float dv = dinv[gd];
            const float* xd = xw + (size_t)gd * EM + pass * 10;
            float r[10];
#pragma unroll
            for (int j = 0; j < 10; ++j)
                r[j] = dv * fmaf(xd[j], dv, acc[j]) + b[pass * 10 + j];
            if (pass == 0) {
                float* o = out1p0 + (size_t)gd * 10;
#pragma unroll
                for (int j = 0; j < 10; ++j) o[j] = r[j];
            } else {
                float r0[10];
                float ss = 0.f;
                const float* o0 = out1p0 + (size_t)gd * 10;
#pragma unroll
                for (int j = 0; j < 10; ++j) { r0[j] = o0[j]; ss = fmaf(r0[j], r0[j], ss); }
#pragma unroll
                for (int j = 0; j < 10; ++j) ss = fmaf(r[j], r[j], ss);
                float inv = 1.0f / fmaxf(sqrtf(ss), 1e-12f);
                float* o = embed + (size_t)gd * EM;
#pragma unroll
                for (int j = 0; j < 10; ++j) {
                    float e0 = r0[j] * inv;
                    float e1 = r[j] * inv;
                    o[j]      = e0 > 0.f ? e0 : 0.f;
                    o[10 + j] = e1 > 0.f ? e1 : 0.f;
                }
            }
        }
    }
}

// ---------------- graph boundaries (batch sorted) ----------------
__global__ void k_bound(const int* __restrict__ batch, int* __restrict__ gstart) {
    int n = blockIdx.x * 256 + threadIdx.x;
    if (n >= NN) return;
    int bn = batch[n];
    if (n == 0) {
        for (int g = 0; g <= bn; ++g) gstart[g] = 0;
    } else {
        int bp = batch[n - 1];
        for (int g = bp + 1; g <= bn; ++g) gstart[g] = n;
    }
    if (n == NN - 1) {
        for (int g = bn + 1; g <= NG; ++g) gstart[g] = NN;
    }
}

// ---------------- per-graph pool (max+mean) + final linear ----------------
__global__ void k_poolfinal(const float* __restrict__ embed, const int* __restrict__ gstart,
                            const float* __restrict__ lw, const float* __restrict__ lb,
                            float* __restrict__ out) {
    __shared__ float cross[4][40];
    __shared__ float pooled[40];
    int g = blockIdx.x;
    int s0 = gstart[g], s1 = gstart[g + 1];
    int cnt = s1 - s0;
    float mx[EM], sm[EM];
#pragma unroll
    for (int j = 0; j < EM; ++j) { mx[j] = 0.f; sm[j] = 0.f; }
    for (int n = s0 + threadIdx.x; n < s1; n += 256) {
        const float4* e = (const float4*)(embed + (size_t)n * EM);
#pragma unroll
        for (int c = 0; c < 5; ++c) {
            float4 v = e[c];
            int j = c * 4;
            mx[j+0] = fmaxf(mx[j+0], v.x); sm[j+0] += v.x;
            mx[j+1] = fmaxf(mx[j+1], v.y); sm[j+1] += v.y;
            mx[j+2] = fmaxf(mx[j+2], v.z); sm[j+2] += v.z;
            mx[j+3] = fmaxf(mx[j+3], v.w); sm[j+3] += v.w;
        }
    }
#pragma unroll
    for (int o = 32; o > 0; o >>= 1) {
#pragma unroll
        for (int j = 0; j < EM; ++j) {
            mx[j] = fmaxf(mx[j], __shfl_xor(mx[j], o));
            sm[j] += __shfl_xor(sm[j], o);
        }
    }
    int wave = threadIdx.x >> 6, lane = threadIdx.x & 63;
    if (lane == 0) {
#pragma unroll
        for (int j = 0; j < EM; ++j) { cross[wave][j] = mx[j]; cross[wave][EM + j] = sm[j]; }
    }
    __syncthreads();
    if (threadIdx.x < 40) {
        int j = threadIdx.x;
        float v = cross[0][j];
        if (j < EM) v = fmaxf(fmaxf(v, cross[1][j]), fmaxf(cross[2][j], cross[3][j]));
        else        v = v + cross[1][j] + cross[2][j] + cross[3][j];
        if (j >= EM) v *= 1.0f / fmaxf((float)cnt, 1.0f);
        pooled[j] = v;
    }
    __syncthreads();
    if (threadIdx.x < NC) {
        int c = threadIdx.x;
        float acc = lb[c];
#pragma unroll
        for (int j = 0; j < 2 * EM; ++j) acc = fmaf(pooled[j], lw[j * NC + c], acc);
        out[g * NC + c] = acc;
    }
}

extern "C" void kernel_launch(void* const* d_in, const int* in_sizes, int n_in,
                              void* d_out, int out_size, void* d_ws, size_t ws_size,
                              hipStream_t stream) {
    const float* x     = (const float*)d_in[0];
    const int*   ei    = (const int*)d_in[1];
    const float* ew    = (const float*)d_in[2];
    const int*   batch = (const int*)d_in[3];
    const float* W     = (const float*)d_in[4];
    const float* b     = (const float*)d_in[5];
    const float* lw    = (const float*)d_in[6];
    const float* lb    = (const float*)d_in[7];
    float* out = (float*)d_out;

    char* ws = (char*)d_ws;
    int*    gcursor = (int*)ws;    ws += 4096;
    int*    gstart  = (int*)ws;    ws += 1024;
    int*    rowptrs = (int*)ws;    ws += (size_t)NB * 129 * 4 + 512;  // 403 KB
    float*  dinv    = (float*)ws;  ws += (size_t)NN * 4;              // 400 KB
    float*  xw      = (float*)ws;  ws += (size_t)NN * EM * 4;         // 8 MB
    __half* xwh     = (__half*)ws; ws += 2 * PLANE_HALVES * 2;        // 6.4 MB
    float*  out1p0  = (float*)ws;  ws += (size_t)NN * 10 * 4;         // 4 MB
    float*  embed   = (float*)ws;  ws += (size_t)NN * EM * 4;         // 8 MB
    uint2*  barr    = (uint2*)ws;                                     // 28.8 MB
    unsigned long long* barr64 = (unsigned long long*)barr;

    const int* srcp = ei;
    const int* dstp = ei + NE;

    (void)hipMemsetAsync(gcursor, 0, 4096, stream);
    k_scatter<<<(NE + T - 1) / T, SBLK, 0, stream>>>(srcp, dstp, ew, gcursor, barr);
    k_sortb<<<NB, 1024, 0, stream>>>(gcursor, barr64, rowptrs, dinv);
    k_fix<<<NB, 256, 0, stream>>>(gcursor, barr, dinv);
    k_xw<<<(NN + 63) / 64, 256, 0, stream>>>(x, W, xw, xwh);
    k_aggr2<<<NB, 512, 0, stream>>>(rowptrs, barr64, xwh, dinv, xw, b, out1p0, embed, 0);
    k_aggr2<<<NB, 512, 0, stream>>>(rowptrs, barr64, xwh, dinv, xw, b, out1p0, embed, 1);
    k_bound<<<(NN + 255) / 256, 256, 0, stream>>>(batch, gstart);
    k_poolfinal<<<NG, 256, 0, stream>>>(embed, gstart, lw, lb, out);
}

// Round 8
// 314.267 us; speedup vs baseline: 2.1653x; 1.1242x over previous
//
#include <hip/hip_runtime.h>
#include <hip/hip_fp16.h>

#define NN 100000   // nodes
#define NE 3200000  // edges
#define NF 128      // in features
#define EM 20       // embed
#define NC 10       // classes
#define NG 64       // graphs

#define NB 782      // dst buckets of 128 nodes
#define CAPB 4608   // per-bucket capacity (mean 4096, +8 sigma)
#define T 4096      // edges per scatter block
#define SBLK 512    // scatter block threads

#define PLANE_HALVES ((size_t)NN * 16)  // fp16 plane: 16 halves (32B) per node, 10 used

// ---------------- bucketed counting-sort scatter ----------------
__global__ void k_scatter(const int* __restrict__ src, const int* __restrict__ dst,
                          const float* __restrict__ w, int* __restrict__ gcursor,
                          uint2* __restrict__ barr) {
    __shared__ unsigned int cnt[NB];
    __shared__ unsigned int off[NB];
    __shared__ unsigned int gbase[NB];
    __shared__ uint2 staged[T];                 // aliased as scan scratch (disjoint phases)
    __shared__ unsigned short bkt[T];
    unsigned int* scratch = (unsigned int*)staged;
    int tid = threadIdx.x;
    long E0 = (long)blockIdx.x * T;
    int tot = (int)min((long)T, (long)NE - E0);
    for (int i = tid; i < NB; i += SBLK) cnt[i] = 0;
    for (int i = tid; i < 1024; i += SBLK) scratch[i] = 0;
    __syncthreads();
    for (int k = 0; k < T / SBLK; ++k) {
        int e = k * SBLK + tid;
        if (e < tot) atomicAdd(&cnt[((unsigned)dst[E0 + e]) >> 7], 1u);
    }
    __syncthreads();
    for (int i = tid; i < NB; i += SBLK) scratch[i] = cnt[i];
    __syncthreads();
    for (int d = 1; d < 1024; d <<= 1) {
        unsigned int v[1024 / SBLK];
#pragma unroll
        for (int q = 0; q < 1024 / SBLK; ++q) {
            int idx = q * SBLK + tid;
            v[q] = (idx >= d) ? scratch[idx - d] : 0u;
        }
        __syncthreads();
#pragma unroll
        for (int q = 0; q < 1024 / SBLK; ++q) scratch[q * SBLK + tid] += v[q];
        __syncthreads();
    }
    for (int i = tid; i < NB; i += SBLK) off[i] = scratch[i] - cnt[i];
    __syncthreads();
    for (int i = tid; i < NB; i += SBLK) {
        unsigned int c = cnt[i];
        gbase[i] = c ? (unsigned int)atomicAdd(&gcursor[i], (int)c) : 0u;
        cnt[i] = 0;
    }
    __syncthreads();
    for (int k = 0; k < T / SBLK; ++k) {
        int e = k * SBLK + tid;
        if (e < tot) {
            long ge = E0 + e;
            unsigned int d = (unsigned)dst[ge];
            unsigned int b = d >> 7;
            unsigned int slot = atomicAdd(&cnt[b], 1u);
            unsigned int pos = off[b] + slot;
            staged[pos] = make_uint2((((unsigned)src[ge]) << 7) | (d & 127u),
                                     __float_as_uint(w[ge]));
            bkt[pos] = (unsigned short)b;
        }
    }
    __syncthreads();
    for (int i = tid; i < tot; i += SBLK) {
        unsigned int b = bkt[i];
        unsigned int gpos = gbase[b] + ((unsigned)i - off[b]);
        if (gpos < CAPB) barr[(size_t)b * CAPB + gpos] = staged[i];
    }
}

// ---------------- per-bucket dl-sort -> CSR rowptr + dinv ----------------
__global__ __launch_bounds__(1024) void k_sortb(const int* __restrict__ gcursor,
                                                unsigned long long* __restrict__ barr64,
                                                int* __restrict__ rowptrs,
                                                float* __restrict__ dinv) {
    __shared__ unsigned long long srt[CAPB];
    __shared__ unsigned int cnt[128];
    __shared__ unsigned int off[128];
    int bk = blockIdx.x, tid = threadIdx.x;
    if (tid < 128) cnt[tid] = 0;
    __syncthreads();
    int cntb = min(gcursor[bk], CAPB);
    unsigned long long* row = barr64 + (size_t)bk * CAPB;
    unsigned long long rec[5];
    unsigned int pos[5];
    int K = 0;
    for (int e = tid; e < cntb; e += 1024) {
        rec[K] = row[e];
        pos[K] = atomicAdd(&cnt[(unsigned)rec[K] & 127u], 1u);
        ++K;
    }
    __syncthreads();
    if (tid < 128) off[tid] = cnt[tid];
    __syncthreads();
    for (int d = 1; d < 128; d <<= 1) {
        unsigned int v = 0;
        if (tid < 128 && tid >= (unsigned)d) v = off[tid - d];
        __syncthreads();
        if (tid < 128 && tid >= (unsigned)d) off[tid] += v;
        __syncthreads();
    }
    for (int k = 0; k < K; ++k) {
        unsigned int dl = (unsigned)rec[k] & 127u;
        srt[off[dl] - cnt[dl] + pos[k]] = rec[k];
    }
    __syncthreads();
    for (int e = tid; e < cntb; e += 1024) row[e] = srt[e];
    if (tid < 128) rowptrs[bk * 129 + tid] = (int)(off[tid] - cnt[tid]);
    if (tid == 0) rowptrs[bk * 129 + 128] = cntb;
    if (tid < 128) {
        unsigned int s0 = off[tid] - cnt[tid], s1 = off[tid];
        float s = 1.0f;  // self-loop
        for (unsigned int i = s0; i < s1; ++i)
            s += __uint_as_float((unsigned int)(srt[i] >> 32));
        int gd = bk * 128 + tid;
        if (gd < NN) dinv[gd] = rsqrtf(s);
    }
}

// ---------------- xw = x @ W, LDS-tiled; emits dinv-prescaled fp16 planes ----------------
// plane value = xw[n][j] * dinv[n]  (removes both k_fix and the hot-loop dinv gather)
__global__ void k_xw(const float* __restrict__ x, const float* __restrict__ W,
                     const float* __restrict__ dinv,
                     float* __restrict__ xw, __half* __restrict__ xwh) {
    __shared__ float xs[64 * 129];
    __shared__ float Ws[NF * EM];
    int base = blockIdx.x * 64;
    for (int i = threadIdx.x; i < NF * EM; i += 256) Ws[i] = W[i];
    const float4* xg = (const float4*)(x + (size_t)base * NF);
    for (int v = threadIdx.x; v < 64 * NF / 4; v += 256) {
        int fidx = v * 4;
        size_t gidx = (size_t)base * NF + fidx;
        float4 val = (gidx + 3 < (size_t)NN * NF) ? xg[v] : make_float4(0.f, 0.f, 0.f, 0.f);
        int r = fidx / NF, c = fidx % NF;
        float* p = xs + r * 129 + c;
        p[0] = val.x; p[1] = val.y; p[2] = val.z; p[3] = val.w;
    }
    __syncthreads();
    int n = threadIdx.x & 63;
    int jg = threadIdx.x >> 6;       // 0..3
    int j0 = jg * 5;
    if (base + n >= NN) return;
    float acc[5] = {0.f, 0.f, 0.f, 0.f, 0.f};
    const float* xr = xs + n * 129;
#pragma unroll 4
    for (int k = 0; k < NF; ++k) {
        float xv = xr[k];
        const float* wr = Ws + k * EM + j0;
#pragma unroll
        for (int jj = 0; jj < 5; ++jj) acc[jj] = fmaf(xv, wr[jj], acc[jj]);
    }
    float* o = xw + (size_t)(base + n) * EM + j0;
#pragma unroll
    for (int jj = 0; jj < 5; ++jj) o[jj] = acc[jj];
    float dv = dinv[base + n];
    __half* ph = xwh + (size_t)(jg >> 1) * PLANE_HALVES + (size_t)(base + n) * 16 + (jg & 1) * 5;
#pragma unroll
    for (int jj = 0; jj < 5; ++jj) ph[jj] = __float2half(acc[jj] * dv);
}

// ---------------- CSR aggregate, register accumulation, no atomics ----------------
// 4 threads per dst; plane is dinv-prescaled so nw = raw edge weight.
__global__ void k_aggr2(const int* __restrict__ rowptrs, const unsigned long long* __restrict__ barr64,
                        const __half* __restrict__ xwh, const float* __restrict__ dinv,
                        const float* __restrict__ xw, const float* __restrict__ b,
                        float* __restrict__ out1p0, float* __restrict__ embed, int pass) {
    int bk = blockIdx.x, tid = threadIdx.x;   // 512 threads
    int d = tid >> 2, sub = tid & 3;
    int s0 = rowptrs[bk * 129 + d], s1 = rowptrs[bk * 129 + d + 1];
    const unsigned long long* row = barr64 + (size_t)bk * CAPB;
    const uint4* plane4 = (const uint4*)(xwh + (size_t)pass * PLANE_HALVES);
    const uint*  plane1 = (const uint*)plane4;
    float acc[10];
#pragma unroll
    for (int j = 0; j < 10; ++j) acc[j] = 0.f;
    int e = s0 + sub;
    for (; e + 4 < s1; e += 8) {
        // two independent gathers in flight
        unsigned long long r0 = row[e];
        unsigned long long r1 = row[e + 4];
        unsigned int sa = ((unsigned int)r0) >> 7;
        unsigned int sb = ((unsigned int)r1) >> 7;
        float nwa = __uint_as_float((unsigned int)(r0 >> 32));
        float nwb = __uint_as_float((unsigned int)(r1 >> 32));
        uint4 h4a = plane4[(size_t)sa * 2];
        uint4 h4b = plane4[(size_t)sb * 2];
        uint  h2a = plane1[(size_t)sa * 8 + 4];
        uint  h2b = plane1[(size_t)sb * 8 + 4];
        const __half2* ha = (const __half2*)&h4a;
        const __half2* hb = (const __half2*)&h4b;
#pragma unroll
        for (int c = 0; c < 4; ++c) {
            float2 fa = __half22float2(ha[c]);
            float2 fb = __half22float2(hb[c]);
            acc[2*c]   = fmaf(fa.x, nwa, acc[2*c]);
            acc[2*c+1] = fmaf(fa.y, nwa, acc[2*c+1]);
            acc[2*c]   = fmaf(fb.x, nwb, acc[2*c]);
            acc[2*c+1] = fmaf(fb.y, nwb, acc[2*c+1]);
        }
        float2 fa4 = __half22float2(*(const __half2*)&h2a);
        float2 fb4 = __half22float2(*(const __half2*)&h2b);
        acc[8] = fmaf(fa4.x, nwa, acc[8]); acc[9] = fmaf(fa4.y, nwa, acc[9]);
        acc[8] = fmaf(fb4.x, nwb, acc[8]); acc[9] = fmaf(fb4.y, nwb, acc[9]);
    }
    for (; e < s1; e += 4) {
        unsigned long long r = row[e];
        unsigned int s = ((unsigned int)r) >> 7;
        float nw = __uint_as_float((unsigned int)(r >> 32));
        uint4 h4 = plane4[(size_t)s * 2];
        uint  h2 = plane1[(size_t)s * 8 + 4];
        const __half2* hh = (const __half2*)&h4;
#pragma unroll
        for (int c = 0; c < 4; ++c) {
            float2 f = __half22float2(hh[c]);
            acc[2*c]   = fmaf(f.x, nw, acc[2*c]);
            acc[2*c+1] = fmaf(f.y, nw, acc[2*c+1]);
        }
        float2 f4 = __half22float2(*(const __half2*)&h2);
        acc[8] = fmaf(f4.x, nw, acc[8]); acc[9] = fmaf(f4.y, nw, acc[9]);
    }
#pragma unroll
    for (int j = 0; j < 10; ++j) {
        acc[j] += __shfl_xor(acc[j], 1);
        acc[j] += __shfl_xor(acc[j], 2);
    }
    if (sub == 0) {
        int gd = bk * 128 + d;
        if (gd < NN) {
            float dv = dinv[gd];
            const float* xd = xw + (size_t)gd * EM + pass * 10;
            float r[10];
#pragma unroll
            for (int j = 0; j < 10; ++j)
                r[j] = dv * fmaf(xd[j], dv, acc[j]) + b[pass * 10 + j];
            if (pass == 0) {
                float* o = out1p0 + (size_t)gd * 10;
#pragma unroll
                for (int j = 0; j < 10; ++j) o[j] = r[j];
            } else {
                float r0[10];
                float ss = 0.f;
                const float* o0 = out1p0 + (size_t)gd * 10;
#pragma unroll
                for (int j = 0; j < 10; ++j) { r0[j] = o0[j]; ss = fmaf(r0[j], r0[j], ss); }
#pragma unroll
                for (int j = 0; j < 10; ++j) ss = fmaf(r[j], r[j], ss);
                float inv = 1.0f / fmaxf(sqrtf(ss), 1e-12f);
                float* o = embed + (size_t)gd * EM;
#pragma unroll
                for (int j = 0; j < 10; ++j) {
                    float e0 = r0[j] * inv;
                    float e1 = r[j] * inv;
                    o[j]      = e0 > 0.f ? e0 : 0.f;
                    o[10 + j] = e1 > 0.f ? e1 : 0.f;
                }
            }
        }
    }
}

// ---------------- graph boundaries (batch sorted) ----------------
__global__ void k_bound(const int* __restrict__ batch, int* __restrict__ gstart) {
    int n = blockIdx.x * 256 + threadIdx.x;
    if (n >= NN) return;
    int bn = batch[n];
    if (n == 0) {
        for (int g = 0; g <= bn; ++g) gstart[g] = 0;
    } else {
        int bp = batch[n - 1];
        for (int g = bp + 1; g <= bn; ++g) gstart[g] = n;
    }
    if (n == NN - 1) {
        for (int g = bn + 1; g <= NG; ++g) gstart[g] = NN;
    }
}

// ---------------- per-graph pool (max+mean) + final linear ----------------
__global__ void k_poolfinal(const float* __restrict__ embed, const int* __restrict__ gstart,
                            const float* __restrict__ lw, const float* __restrict__ lb,
                            float* __restrict__ out) {
    __shared__ float cross[4][40];
    __shared__ float pooled[40];
    int g = blockIdx.x;
    int s0 = gstart[g], s1 = gstart[g + 1];
    int cnt = s1 - s0;
    float mx[EM], sm[EM];
#pragma unroll
    for (int j = 0; j < EM; ++j) { mx[j] = 0.f; sm[j] = 0.f; }
    for (int n = s0 + threadIdx.x; n < s1; n += 256) {
        const float4* e = (const float4*)(embed + (size_t)n * EM);
#pragma unroll
        for (int c = 0; c < 5; ++c) {
            float4 v = e[c];
            int j = c * 4;
            mx[j+0] = fmaxf(mx[j+0], v.x); sm[j+0] += v.x;
            mx[j+1] = fmaxf(mx[j+1], v.y); sm[j+1] += v.y;
            mx[j+2] = fmaxf(mx[j+2], v.z); sm[j+2] += v.z;
            mx[j+3] = fmaxf(mx[j+3], v.w); sm[j+3] += v.w;
        }
    }
#pragma unroll
    for (int o = 32; o > 0; o >>= 1) {
#pragma unroll
        for (int j = 0; j < EM; ++j) {
            mx[j] = fmaxf(mx[j], __shfl_xor(mx[j], o));
            sm[j] += __shfl_xor(sm[j], o);
        }
    }
    int wave = threadIdx.x >> 6, lane = threadIdx.x & 63;
    if (lane == 0) {
#pragma unroll
        for (int j = 0; j < EM; ++j) { cross[wave][j] = mx[j]; cross[wave][EM + j] = sm[j]; }
    }
    __syncthreads();
    if (threadIdx.x < 40) {
        int j = threadIdx.x;
        float v = cross[0][j];
        if (j < EM) v = fmaxf(fmaxf(v, cross[1][j]), fmaxf(cross[2][j], cross[3][j]));
        else        v = v + cross[1][j] + cross[2][j] + cross[3][j];
        if (j >= EM) v *= 1.0f / fmaxf((float)cnt, 1.0f);
        pooled[j] = v;
    }
    __syncthreads();
    if (threadIdx.x < NC) {
        int c = threadIdx.x;
        float acc = lb[c];
#pragma unroll
        for (int j = 0; j < 2 * EM; ++j) acc = fmaf(pooled[j], lw[j * NC + c], acc);
        out[g * NC + c] = acc;
    }
}

extern "C" void kernel_launch(void* const* d_in, const int* in_sizes, int n_in,
                              void* d_out, int out_size, void* d_ws, size_t ws_size,
                              hipStream_t stream) {
    const float* x     = (const float*)d_in[0];
    const int*   ei    = (const int*)d_in[1];
    const float* ew    = (const float*)d_in[2];
    const int*   batch = (const int*)d_in[3];
    const float* W     = (const float*)d_in[4];
    const float* b     = (const float*)d_in[5];
    const float* lw    = (const float*)d_in[6];
    const float* lb    = (const float*)d_in[7];
    float* out = (float*)d_out;

    char* ws = (char*)d_ws;
    int*    gcursor = (int*)ws;    ws += 4096;
    int*    gstart  = (int*)ws;    ws += 1024;
    int*    rowptrs = (int*)ws;    ws += (size_t)NB * 129 * 4 + 512;  // 403 KB
    float*  dinv    = (float*)ws;  ws += (size_t)NN * 4;              // 400 KB
    float*  xw      = (float*)ws;  ws += (size_t)NN * EM * 4;         // 8 MB
    __half* xwh     = (__half*)ws; ws += 2 * PLANE_HALVES * 2;        // 6.4 MB
    float*  out1p0  = (float*)ws;  ws += (size_t)NN * 10 * 4;         // 4 MB
    float*  embed   = (float*)ws;  ws += (size_t)NN * EM * 4;         // 8 MB
    uint2*  barr    = (uint2*)ws;                                     // 28.8 MB
    unsigned long long* barr64 = (unsigned long long*)barr;

    const int* srcp = ei;
    const int* dstp = ei + NE;

    (void)hipMemsetAsync(gcursor, 0, 4096, stream);
    k_scatter<<<(NE + T - 1) / T, SBLK, 0, stream>>>(srcp, dstp, ew, gcursor, barr);
    k_sortb<<<NB, 1024, 0, stream>>>(gcursor, barr64, rowptrs, dinv);
    k_xw<<<(NN + 63) / 64, 256, 0, stream>>>(x, W, dinv, xw, xwh);
    k_aggr2<<<NB, 512, 0, stream>>>(rowptrs, barr64, xwh, dinv, xw, b, out1p0, embed, 0);
    k_aggr2<<<NB, 512, 0, stream>>>(rowptrs, barr64, xwh, dinv, xw, b, out1p0, embed, 1);
    k_bound<<<(NN + 255) / 256, 256, 0, stream>>>(batch, gstart);
    k_poolfinal<<<NG, 256, 0, stream>>>(embed, gstart, lw, lb, out);
}

// Round 9
// 266.263 us; speedup vs baseline: 2.5557x; 1.1803x over previous
//
#include <hip/hip_runtime.h>
#include <hip/hip_fp16.h>

#define NN 100000   // nodes
#define NE 3200000  // edges
#define NF 128      // in features
#define EM 20       // embed
#define NC 10       // classes
#define NG 64       // graphs

#define NB 782      // dst buckets of 128 nodes
#define CAPB 4608   // per-bucket capacity (mean 4096, +8 sigma)
#define T 4096      // edges per scatter block
#define SBLK 512    // scatter block threads

#define ROWH 24     // fp16 halves per node row (48B, 16B-aligned; 20 used)

// ---------------- bucketed counting-sort scatter ----------------
// dst cached in VGPRs; wave-shfl scan (3 barriers instead of 20)
__global__ __launch_bounds__(SBLK) void k_scatter(
        const int* __restrict__ src, const int* __restrict__ dst,
        const float* __restrict__ w, int* __restrict__ gcursor,
        uint2* __restrict__ barr) {
    __shared__ unsigned int cnt[1024];
    __shared__ unsigned int off[1024];
    __shared__ unsigned int gbase[NB];
    __shared__ unsigned int wsum[8];
    __shared__ uint2 staged[T];
    __shared__ unsigned short bkt[T];
    int tid = threadIdx.x;
    long E0 = (long)blockIdx.x * T;
    int tot = (int)min((long)T, (long)NE - E0);
    // p1: zero padded histogram
    for (int i = tid; i < 1024; i += SBLK) cnt[i] = 0;
    __syncthreads();
    // p2: histogram; cache dst in VGPRs
    unsigned int dreg[T / SBLK];
#pragma unroll
    for (int k = 0; k < T / SBLK; ++k) {
        int e = k * SBLK + tid;
        dreg[k] = 0;
        if (e < tot) {
            dreg[k] = (unsigned)dst[E0 + e];
            atomicAdd(&cnt[dreg[k] >> 7], 1u);
        }
    }
    __syncthreads();
    // p3: exclusive scan of cnt[0..1024) via wave shfl (each thread: elems 2t, 2t+1)
    {
        int lane = tid & 63, wv = tid >> 6;
        unsigned int v0 = cnt[tid * 2], v1 = cnt[tid * 2 + 1];
        unsigned int ps = v0 + v1;
        unsigned int ips = ps;
#pragma unroll
        for (int o = 1; o < 64; o <<= 1) {
            unsigned int t = __shfl_up(ips, o);
            if (lane >= o) ips += t;
        }
        if (lane == 63) wsum[wv] = ips;
        __syncthreads();
        if (tid == 0) {
            unsigned int a = 0;
#pragma unroll
            for (int i = 0; i < 8; ++i) { unsigned int t = wsum[i]; wsum[i] = a; a += t; }
        }
        __syncthreads();
        unsigned int base = wsum[wv] + (ips - ps);   // exclusive elem prefix
        off[tid * 2] = base;
        off[tid * 2 + 1] = base + v0;
    }
    // p4: reserve global segments; reset cnt as running slot counter
    // (no barrier needed before: each thread reads cnt[i] it alone resets,
    //  and off[] writes are covered by the barrier below before p5 reads)
    __syncthreads();
    for (int i = tid; i < NB; i += SBLK) {
        unsigned int c = cnt[i];
        gbase[i] = c ? (unsigned int)atomicAdd(&gcursor[i], (int)c) : 0u;
        cnt[i] = 0;
    }
    __syncthreads();
    // p5: stage records grouped by bucket
#pragma unroll
    for (int k = 0; k < T / SBLK; ++k) {
        int e = k * SBLK + tid;
        if (e < tot) {
            long ge = E0 + e;
            unsigned int d = dreg[k];
            unsigned int b = d >> 7;
            unsigned int slot = atomicAdd(&cnt[b], 1u);
            unsigned int pos = off[b] + slot;
            staged[pos] = make_uint2((((unsigned)src[ge]) << 7) | (d & 127u),
                                     __float_as_uint(w[ge]));
            bkt[pos] = (unsigned short)b;
        }
    }
    __syncthreads();
    // p6: coalesced run-flush
    for (int i = tid; i < tot; i += SBLK) {
        unsigned int b = bkt[i];
        unsigned int gpos = gbase[b] + ((unsigned)i - off[b]);
        if (gpos < CAPB) barr[(size_t)b * CAPB + gpos] = staged[i];
    }
}

// ---------------- per-bucket dl-sort -> CSR rowptr + dinv ----------------
__global__ __launch_bounds__(1024) void k_sortb(const int* __restrict__ gcursor,
                                                unsigned long long* __restrict__ barr64,
                                                int* __restrict__ rowptrs,
                                                float* __restrict__ dinv) {
    __shared__ unsigned long long srt[CAPB];
    __shared__ unsigned int cnt[128];
    __shared__ unsigned int off[128];
    int bk = blockIdx.x, tid = threadIdx.x;
    if (tid < 128) cnt[tid] = 0;
    __syncthreads();
    int cntb = min(gcursor[bk], CAPB);
    unsigned long long* row = barr64 + (size_t)bk * CAPB;
    unsigned long long rec[5];
    unsigned int pos[5];
    int K = 0;
    for (int e = tid; e < cntb; e += 1024) {
        rec[K] = row[e];
        pos[K] = atomicAdd(&cnt[(unsigned)rec[K] & 127u], 1u);
        ++K;
    }
    __syncthreads();
    if (tid < 128) off[tid] = cnt[tid];
    __syncthreads();
    for (int d = 1; d < 128; d <<= 1) {
        unsigned int v = 0;
        if (tid < 128 && tid >= (unsigned)d) v = off[tid - d];
        __syncthreads();
        if (tid < 128 && tid >= (unsigned)d) off[tid] += v;
        __syncthreads();
    }
    for (int k = 0; k < K; ++k) {
        unsigned int dl = (unsigned)rec[k] & 127u;
        srt[off[dl] - cnt[dl] + pos[k]] = rec[k];
    }
    __syncthreads();
    for (int e = tid; e < cntb; e += 1024) row[e] = srt[e];
    if (tid < 128) rowptrs[bk * 129 + tid] = (int)(off[tid] - cnt[tid]);
    if (tid == 0) rowptrs[bk * 129 + 128] = cntb;
    if (tid < 128) {
        unsigned int s0 = off[tid] - cnt[tid], s1 = off[tid];
        float s = 1.0f;  // self-loop
        for (unsigned int i = s0; i < s1; ++i)
            s += __uint_as_float((unsigned int)(srt[i] >> 32));
        int gd = bk * 128 + tid;
        if (gd < NN) dinv[gd] = rsqrtf(s);
    }
}

// ---------------- xw = x @ W -> dinv-prescaled fp16 rows (48B/node) ----------------
__global__ void k_xw(const float* __restrict__ x, const float* __restrict__ W,
                     const float* __restrict__ dinv, __half* __restrict__ xwh) {
    __shared__ float xs[64 * 129];
    __shared__ float Ws[NF * EM];
    int base = blockIdx.x * 64;
    for (int i = threadIdx.x; i < NF * EM; i += 256) Ws[i] = W[i];
    const float4* xg = (const float4*)(x + (size_t)base * NF);
    for (int v = threadIdx.x; v < 64 * NF / 4; v += 256) {
        int fidx = v * 4;
        size_t gidx = (size_t)base * NF + fidx;
        float4 val = (gidx + 3 < (size_t)NN * NF) ? xg[v] : make_float4(0.f, 0.f, 0.f, 0.f);
        int r = fidx / NF, c = fidx % NF;
        float* p = xs + r * 129 + c;
        p[0] = val.x; p[1] = val.y; p[2] = val.z; p[3] = val.w;
    }
    __syncthreads();
    int n = threadIdx.x & 63;
    int jg = threadIdx.x >> 6;       // 0..3 -> dims jg*5..jg*5+4
    int j0 = jg * 5;
    if (base + n >= NN) return;
    float acc[5] = {0.f, 0.f, 0.f, 0.f, 0.f};
    const float* xr = xs + n * 129;
#pragma unroll 4
    for (int k = 0; k < NF; ++k) {
        float xv = xr[k];
        const float* wr = Ws + k * EM + j0;
#pragma unroll
        for (int jj = 0; jj < 5; ++jj) acc[jj] = fmaf(xv, wr[jj], acc[jj]);
    }
    float dv = dinv[base + n];
    __half* ph = xwh + (size_t)(base + n) * ROWH + j0;
#pragma unroll
    for (int jj = 0; jj < 5; ++jj) ph[jj] = __float2half(acc[jj] * dv);
}

__device__ inline void unpack20(uint4 a, uint4 bq, uint2 cq, float* f) {
    const __half2* h = (const __half2*)&a;
#pragma unroll
    for (int c = 0; c < 4; ++c) { float2 t = __half22float2(h[c]); f[2*c] = t.x; f[2*c+1] = t.y; }
    h = (const __half2*)&bq;
#pragma unroll
    for (int c = 0; c < 4; ++c) { float2 t = __half22float2(h[c]); f[8+2*c] = t.x; f[9+2*c] = t.y; }
    h = (const __half2*)&cq;
#pragma unroll
    for (int c = 0; c < 2; ++c) { float2 t = __half22float2(h[c]); f[16+2*c] = t.x; f[17+2*c] = t.y; }
}

// ---------------- single-pass CSR aggregate + fused epilogue ----------------
// 4 threads per dst, register accumulation over all 20 dims, no atomics.
__global__ __launch_bounds__(512) void k_aggr(
        const int* __restrict__ rowptrs, const unsigned long long* __restrict__ barr64,
        const __half* __restrict__ xwh, const float* __restrict__ dinv,
        const float* __restrict__ b, float* __restrict__ embed) {
    int bk = blockIdx.x, tid = threadIdx.x;   // 512 threads
    int d = tid >> 2, sub = tid & 3;
    int s0 = rowptrs[bk * 129 + d], s1 = rowptrs[bk * 129 + d + 1];
    const unsigned long long* row = barr64 + (size_t)bk * CAPB;
    const uint4* plane = (const uint4*)xwh;   // node row = 3 uint4 (48B)
    float acc[20];
#pragma unroll
    for (int j = 0; j < 20; ++j) acc[j] = 0.f;
    for (int e = s0 + sub; e < s1; e += 4) {
        unsigned long long r = row[e];
        unsigned int s = ((unsigned int)r) >> 7;
        float nw = __uint_as_float((unsigned int)(r >> 32));  // raw edge weight
        const uint4* p4 = plane + (size_t)s * 3;
        uint4 a = p4[0];
        uint4 bq = p4[1];
        uint2 cq = *(const uint2*)(p4 + 2);
        float f[20];
        unpack20(a, bq, cq, f);
#pragma unroll
        for (int j = 0; j < 20; ++j) acc[j] = fmaf(f[j], nw, acc[j]);
    }
#pragma unroll
    for (int j = 0; j < 20; ++j) {
        acc[j] += __shfl_xor(acc[j], 1);
        acc[j] += __shfl_xor(acc[j], 2);
    }
    if (sub == 0) {
        int gd = bk * 128 + d;
        if (gd < NN) {
            float dv = dinv[gd];
            const uint4* p4 = plane + (size_t)gd * 3;
            uint4 a = p4[0];
            uint4 bq = p4[1];
            uint2 cq = *(const uint2*)(p4 + 2);
            float xdh[20];
            unpack20(a, bq, cq, xdh);  // = xw[gd][:]*dinv[gd]
            float r[20];
            float ss = 0.f;
#pragma unroll
            for (int j = 0; j < 20; ++j) {
                r[j] = dv * (acc[j] + xdh[j]) + b[j];
                ss = fmaf(r[j], r[j], ss);
            }
            float inv = 1.0f / fmaxf(sqrtf(ss), 1e-12f);
            float4 o4[5];
            float* o = (float*)o4;
#pragma unroll
            for (int j = 0; j < 20; ++j) {
                float e = r[j] * inv;
                o[j] = e > 0.f ? e : 0.f;
            }
            float4* eo = (float4*)(embed + (size_t)gd * EM);
#pragma unroll
            for (int c = 0; c < 5; ++c) eo[c] = o4[c];
        }
    }
}

// ---------------- graph boundaries (batch sorted) ----------------
__global__ void k_bound(const int* __restrict__ batch, int* __restrict__ gstart) {
    int n = blockIdx.x * 256 + threadIdx.x;
    if (n >= NN) return;
    int bn = batch[n];
    if (n == 0) {
        for (int g = 0; g <= bn; ++g) gstart[g] = 0;
    } else {
        int bp = batch[n - 1];
        for (int g = bp + 1; g <= bn; ++g) gstart[g] = n;
    }
    if (n == NN - 1) {
        for (int g = bn + 1; g <= NG; ++g) gstart[g] = NN;
    }
}

// ---------------- per-graph pool (max+mean) + final linear ----------------
__global__ void k_poolfinal(const float* __restrict__ embed, const int* __restrict__ gstart,
                            const float* __restrict__ lw, const float* __restrict__ lb,
                            float* __restrict__ out) {
    __shared__ float cross[4][40];
    __shared__ float pooled[40];
    int g = blockIdx.x;
    int s0 = gstart[g], s1 = gstart[g + 1];
    int cnt = s1 - s0;
    float mx[EM], sm[EM];
#pragma unroll
    for (int j = 0; j < EM; ++j) { mx[j] = 0.f; sm[j] = 0.f; }
    for (int n = s0 + threadIdx.x; n < s1; n += 256) {
        const float4* e = (const float4*)(embed + (size_t)n * EM);
#pragma unroll
        for (int c = 0; c < 5; ++c) {
            float4 v = e[c];
            int j = c * 4;
            mx[j+0] = fmaxf(mx[j+0], v.x); sm[j+0] += v.x;
            mx[j+1] = fmaxf(mx[j+1], v.y); sm[j+1] += v.y;
            mx[j+2] = fmaxf(mx[j+2], v.z); sm[j+2] += v.z;
            mx[j+3] = fmaxf(mx[j+3], v.w); sm[j+3] += v.w;
        }
    }
#pragma unroll
    for (int o = 32; o > 0; o >>= 1) {
#pragma unroll
        for (int j = 0; j < EM; ++j) {
            mx[j] = fmaxf(mx[j], __shfl_xor(mx[j], o));
            sm[j] += __shfl_xor(sm[j], o);
        }
    }
    int wave = threadIdx.x >> 6, lane = threadIdx.x & 63;
    if (lane == 0) {
#pragma unroll
        for (int j = 0; j < EM; ++j) { cross[wave][j] = mx[j]; cross[wave][EM + j] = sm[j]; }
    }
    __syncthreads();
    if (threadIdx.x < 40) {
        int j = threadIdx.x;
        float v = cross[0][j];
        if (j < EM) v = fmaxf(fmaxf(v, cross[1][j]), fmaxf(cross[2][j], cross[3][j]));
        else        v = v + cross[1][j] + cross[2][j] + cross[3][j];
        if (j >= EM) v *= 1.0f / fmaxf((float)cnt, 1.0f);
        pooled[j] = v;
    }
    __syncthreads();
    if (threadIdx.x < NC) {
        int c = threadIdx.x;
        float acc = lb[c];
#pragma unroll
        for (int j = 0; j < 2 * EM; ++j) acc = fmaf(pooled[j], lw[j * NC + c], acc);
        out[g * NC + c] = acc;
    }
}

static inline size_t align_up(size_t v) { return (v + 1023) & ~(size_t)1023; }

extern "C" void kernel_launch(void* const* d_in, const int* in_sizes, int n_in,
                              void* d_out, int out_size, void* d_ws, size_t ws_size,
                              hipStream_t stream) {
    const float* x     = (const float*)d_in[0];
    const int*   ei    = (const int*)d_in[1];
    const float* ew    = (const float*)d_in[2];
    const int*   batch = (const int*)d_in[3];
    const float* W     = (const float*)d_in[4];
    const float* b     = (const float*)d_in[5];
    const float* lw    = (const float*)d_in[6];
    const float* lb    = (const float*)d_in[7];
    float* out = (float*)d_out;

    char* ws = (char*)d_ws;
    int*    gcursor = (int*)ws;    ws += align_up(4096);
    int*    gstart  = (int*)ws;    ws += align_up(1024);
    int*    rowptrs = (int*)ws;    ws += align_up((size_t)NB * 129 * 4);
    float*  dinv    = (float*)ws;  ws += align_up((size_t)NN * 4);
    __half* xwh     = (__half*)ws; ws += align_up((size_t)NN * ROWH * 2);  // 4.8 MB
    float*  embed   = (float*)ws;  ws += align_up((size_t)NN * EM * 4);    // 8 MB
    uint2*  barr    = (uint2*)ws;                                          // 28.8 MB
    unsigned long long* barr64 = (unsigned long long*)barr;

    const int* srcp = ei;
    const int* dstp = ei + NE;

    (void)hipMemsetAsync(gcursor, 0, 4096, stream);
    k_scatter<<<(NE + T - 1) / T, SBLK, 0, stream>>>(srcp, dstp, ew, gcursor, barr);
    k_sortb<<<NB, 1024, 0, stream>>>(gcursor, barr64, rowptrs, dinv);
    k_xw<<<(NN + 63) / 64, 256, 0, stream>>>(x, W, dinv, xwh);
    k_aggr<<<NB, 512, 0, stream>>>(rowptrs, barr64, xwh, dinv, b, embed);
    k_bound<<<(NN + 255) / 256, 256, 0, stream>>>(batch, gstart);
    k_poolfinal<<<NG, 256, 0, stream>>>(embed, gstart, lw, lb, out);
}